// Round 1
// baseline (1129.621 us; speedup 1.0000x reference)
//
#include <hip/hip_runtime.h>
#include <hip/hip_bf16.h>

#define B_ROWS 32768
#define L_DIM 512
#define H_DIM 1024
#define E_DIM 128
#define K_EXP 8
#define NBLK 128   // sort blocks: 32768/256

// ---------------- sort: ids + per-block histogram ----------------
__global__ void k_ids_hist(const float* __restrict__ x, int* __restrict__ ids,
                           int* __restrict__ hist) {
    __shared__ int lh[K_EXP];
    int t = threadIdx.x;
    if (t < K_EXP) lh[t] = 0;
    __syncthreads();
    int i = blockIdx.x * 256 + t;
    int id = (int)x[(size_t)i * (L_DIM + 1) + L_DIM];
    ids[i] = id;
    atomicAdd(&lh[id], 1);
    __syncthreads();
    if (t < K_EXP) hist[blockIdx.x * K_EXP + t] = lh[t];
}

// ---------------- scan: per-block bases, segment starts, tile prefixes ----------------
__global__ void k_scan(const int* __restrict__ hist, int* __restrict__ base,
                       int* __restrict__ seg, int* __restrict__ tp) {
    __shared__ int c[K_EXP];
    __shared__ int sseg[K_EXP + 1];
    int k = threadIdx.x;
    if (k < K_EXP) {
        int run = 0;
        for (int b = 0; b < NBLK; ++b) {
            base[b * K_EXP + k] = run;
            run += hist[b * K_EXP + k];
        }
        c[k] = run;
    }
    __syncthreads();
    if (k == 0) {
        int s = 0, t2 = 0;
        for (int e = 0; e < K_EXP; ++e) {
            sseg[e] = s; seg[e] = s; tp[e] = t2;
            s += c[e]; t2 += (c[e] + 127) >> 7;
        }
        sseg[K_EXP] = s; seg[K_EXP] = s; tp[K_EXP] = t2;
    }
    __syncthreads();
    if (k < K_EXP) {
        int s0 = sseg[k];
        for (int b = 0; b < NBLK; ++b) base[b * K_EXP + k] += s0;
    }
}

// ---------------- stable order within block ----------------
__global__ void k_order(const int* __restrict__ ids, const int* __restrict__ base,
                        int* __restrict__ order) {
    __shared__ int sid[256];
    int t = threadIdx.x;
    int i = blockIdx.x * 256 + t;
    int my = ids[i];
    sid[t] = my;
    __syncthreads();
    int rank = 0;
    for (int j = 0; j < t; ++j) rank += (sid[j] == my) ? 1 : 0;
    order[base[blockIdx.x * K_EXP + my] + rank] = i;
}

// ---------------- gather sorted rows into packed, aligned xs ----------------
__global__ void k_gather(const float* __restrict__ x, const int* __restrict__ order,
                         float* __restrict__ xs) {
    int idx = blockIdx.x * 256 + threadIdx.x;
    int p = idx >> 7;            // 128 float4 per row
    int c4 = (idx & 127) << 2;
    int src = order[p];
    const float* sp = x + (size_t)src * (L_DIM + 1) + c4;  // stride 513: scalar loads
    float4 v;
    v.x = sp[0]; v.y = sp[1]; v.z = sp[2]; v.w = sp[3];
    *(float4*)(xs + (size_t)p * L_DIM + c4) = v;
}

// ---------------- fp32 tiled GEMM: C[M,N] = leaky?(A[M,K]@B[K,N] + bias) ----------------
// 128x128 tile, BK=16, 256 threads, per-thread 2x2 groups of 4x4.
template <bool GROUPED, bool LEAKY>
__launch_bounds__(256)
__global__ void gemm_f32(const float* __restrict__ A, int lda,
                         const float* __restrict__ Bw,
                         const float* __restrict__ bias,
                         float* __restrict__ C, int ldc,
                         int N, int Kd,
                         const int* __restrict__ seg, const int* __restrict__ tp) {
    __shared__ float sA[16][132];
    __shared__ float sB[16][132];
    int t = threadIdx.x;
    int bx = blockIdx.x;
    int n0 = blockIdx.y << 7;
    int m0, mEnd;
    const float* Bp = Bw;
    const float* bp = bias;
    if (GROUPED) {
        if (bx >= tp[K_EXP]) return;
        int e = 0;
        while (bx >= tp[e + 1]) ++e;
        m0 = seg[e] + ((bx - tp[e]) << 7);
        mEnd = seg[e + 1];
        Bp += (size_t)e * Kd * N;
        bp += (size_t)e * N;
    } else {
        m0 = bx << 7;
        mEnd = m0 + 128;
    }

    int lrow = t >> 1, lk = (t & 1) << 3;      // A loader: row 0..127, k-half
    int lbk = t >> 4, lbn = (t & 15) << 3;     // B loader: k 0..15, 8 cols
    int tx = t & 15, ty = t >> 4;

    float acc[2][2][4][4] = {};

    int arow = m0 + lrow;
    if (GROUPED) arow = min(arow, mEnd - 1);
    const float* apBase = A + (size_t)arow * lda + lk;
    const float* bpBase = Bp + (size_t)lbk * N + n0 + lbn;

    for (int kt = 0; kt < Kd; kt += 16) {
        float4 a0 = *(const float4*)(apBase + kt);
        float4 a1 = *(const float4*)(apBase + kt + 4);
        float4 b0 = *(const float4*)(bpBase + (size_t)kt * N);
        float4 b1 = *(const float4*)(bpBase + (size_t)kt * N + 4);
        __syncthreads();
        sA[lk + 0][lrow] = a0.x; sA[lk + 1][lrow] = a0.y;
        sA[lk + 2][lrow] = a0.z; sA[lk + 3][lrow] = a0.w;
        sA[lk + 4][lrow] = a1.x; sA[lk + 5][lrow] = a1.y;
        sA[lk + 6][lrow] = a1.z; sA[lk + 7][lrow] = a1.w;
        *(float4*)&sB[lbk][lbn] = b0;
        *(float4*)&sB[lbk][lbn + 4] = b1;
        __syncthreads();
#pragma unroll
        for (int kk = 0; kk < 16; ++kk) {
            float4 a04 = *(const float4*)&sA[kk][ty << 2];
            float4 a14 = *(const float4*)&sA[kk][64 + (ty << 2)];
            float4 b04 = *(const float4*)&sB[kk][tx << 2];
            float4 b14 = *(const float4*)&sB[kk][64 + (tx << 2)];
            float av[2][4] = {{a04.x, a04.y, a04.z, a04.w}, {a14.x, a14.y, a14.z, a14.w}};
            float bv[2][4] = {{b04.x, b04.y, b04.z, b04.w}, {b14.x, b14.y, b14.z, b14.w}};
#pragma unroll
            for (int gm = 0; gm < 2; ++gm)
#pragma unroll
                for (int i = 0; i < 4; ++i)
#pragma unroll
                    for (int gn = 0; gn < 2; ++gn)
#pragma unroll
                        for (int j = 0; j < 4; ++j)
                            acc[gm][gn][i][j] = fmaf(av[gm][i], bv[gn][j], acc[gm][gn][i][j]);
        }
    }

#pragma unroll
    for (int gm = 0; gm < 2; ++gm)
#pragma unroll
        for (int i = 0; i < 4; ++i) {
            int r = m0 + (gm << 6) + (ty << 2) + i;
            if (!GROUPED || r < mEnd) {
                float* crow = C + (size_t)r * ldc + n0;
#pragma unroll
                for (int gn = 0; gn < 2; ++gn) {
                    int nb = (gn << 6) + (tx << 2);
                    float4 v;
                    v.x = acc[gm][gn][i][0] + bp[n0 + nb + 0];
                    v.y = acc[gm][gn][i][1] + bp[n0 + nb + 1];
                    v.z = acc[gm][gn][i][2] + bp[n0 + nb + 2];
                    v.w = acc[gm][gn][i][3] + bp[n0 + nb + 3];
                    if (LEAKY) {
                        v.x = v.x > 0.f ? v.x : 0.01f * v.x;
                        v.y = v.y > 0.f ? v.y : 0.01f * v.y;
                        v.z = v.z > 0.f ? v.z : 0.01f * v.z;
                        v.w = v.w > 0.f ? v.w : 0.01f * v.w;
                    }
                    *(float4*)(crow + nb) = v;
                }
            }
        }
}

extern "C" void kernel_launch(void* const* d_in, const int* in_sizes, int n_in,
                              void* d_out, int out_size, void* d_ws, size_t ws_size,
                              hipStream_t stream) {
    const float* x   = (const float*)d_in[0];
    const float* We1 = (const float*)d_in[1];
    const float* be1 = (const float*)d_in[2];
    const float* We2 = (const float*)d_in[3];
    const float* be2 = (const float*)d_in[4];
    const float* Wd1 = (const float*)d_in[5];
    const float* bd1 = (const float*)d_in[6];
    const float* Wd2 = (const float*)d_in[7];
    const float* bd2 = (const float*)d_in[8];
    float* out = (float*)d_out;

    char* w = (char*)d_ws;
    auto alloc = [&](size_t bytes) {
        char* p = w;
        w += (bytes + 255) & ~(size_t)255;
        return p;
    };
    int* ids   = (int*)alloc((size_t)B_ROWS * 4);
    int* order = (int*)alloc((size_t)B_ROWS * 4);
    int* hist  = (int*)alloc((size_t)NBLK * K_EXP * 4);
    int* base  = (int*)alloc((size_t)NBLK * K_EXP * 4);
    int* seg   = (int*)alloc((K_EXP + 1) * 4);
    int* tp    = (int*)alloc((K_EXP + 1) * 4);
    float* xs  = (float*)alloc((size_t)B_ROWS * L_DIM * 4);   // 64 MB
    float* z   = (float*)alloc((size_t)B_ROWS * E_DIM * 4);   // 16 MB
    float* h   = (float*)alloc((size_t)B_ROWS * H_DIM * 4);   // 128 MB (reused as hd)

    k_ids_hist<<<NBLK, 256, 0, stream>>>(x, ids, hist);
    k_scan<<<1, 64, 0, stream>>>(hist, base, seg, tp);
    k_order<<<NBLK, 256, 0, stream>>>(ids, base, order);
    k_gather<<<(B_ROWS * (L_DIM / 4)) / 256, 256, 0, stream>>>(x, order, xs);

    // h = leaky(xs @ We1 + be1)   [32768,512]@[512,1024]
    gemm_f32<false, true><<<dim3(B_ROWS / 128, H_DIM / 128), 256, 0, stream>>>(
        xs, L_DIM, We1, be1, h, H_DIM, H_DIM, L_DIM, nullptr, nullptr);
    // z = leaky(h @ We2 + be2)    [32768,1024]@[1024,128]
    gemm_f32<false, true><<<dim3(B_ROWS / 128, E_DIM / 128), 256, 0, stream>>>(
        h, H_DIM, We2, be2, z, E_DIM, E_DIM, H_DIM, nullptr, nullptr);
    // hd = leaky(z @ Wd1[e] + bd1[e])  grouped  [cnt_e,128]@[128,1024]
    gemm_f32<true, true><<<dim3(B_ROWS / 128 + K_EXP, H_DIM / 128), 256, 0, stream>>>(
        z, E_DIM, Wd1, bd1, h, H_DIM, H_DIM, E_DIM, seg, tp);
    // out = hd @ Wd2[e] + bd2[e]       grouped  [cnt_e,1024]@[1024,512]
    gemm_f32<true, false><<<dim3(B_ROWS / 128 + K_EXP, L_DIM / 128), 256, 0, stream>>>(
        h, H_DIM, Wd2, bd2, out, L_DIM, L_DIM, H_DIM, seg, tp);
}

// Round 2
// 224.792 us; speedup vs baseline: 5.0252x; 5.0252x over previous
//
#include <hip/hip_runtime.h>
#include <hip/hip_bf16.h>

#define B_ROWS 32768
#define L_DIM 512
#define H_DIM 1024
#define E_DIM 128
#define K_EXP 8
#define NBLK 128   // sort blocks: 32768/256

typedef __bf16 bf16x8 __attribute__((ext_vector_type(8)));
typedef float f32x4 __attribute__((ext_vector_type(4)));

__device__ __forceinline__ void gload16(const void* src, void* dst) {
    __builtin_amdgcn_global_load_lds(
        (const __attribute__((address_space(1))) unsigned int*)src,
        (__attribute__((address_space(3))) unsigned int*)dst, 16, 0, 0);
}

// ---------------- sort: ids + per-block histogram ----------------
__global__ void k_ids_hist(const float* __restrict__ x, int* __restrict__ ids,
                           int* __restrict__ hist) {
    __shared__ int lh[K_EXP];
    int t = threadIdx.x;
    if (t < K_EXP) lh[t] = 0;
    __syncthreads();
    int i = blockIdx.x * 256 + t;
    int id = (int)x[(size_t)i * (L_DIM + 1) + L_DIM];
    ids[i] = id;
    atomicAdd(&lh[id], 1);
    __syncthreads();
    if (t < K_EXP) hist[blockIdx.x * K_EXP + t] = lh[t];
}

__global__ void k_scan(const int* __restrict__ hist, int* __restrict__ base,
                       int* __restrict__ seg, int* __restrict__ tp) {
    __shared__ int c[K_EXP];
    __shared__ int sseg[K_EXP + 1];
    int k = threadIdx.x;
    if (k < K_EXP) {
        int run = 0;
        for (int b = 0; b < NBLK; ++b) {
            base[b * K_EXP + k] = run;
            run += hist[b * K_EXP + k];
        }
        c[k] = run;
    }
    __syncthreads();
    if (k == 0) {
        int s = 0, t2 = 0;
        for (int e = 0; e < K_EXP; ++e) {
            sseg[e] = s; seg[e] = s; tp[e] = t2;
            s += c[e]; t2 += (c[e] + 127) >> 7;
        }
        sseg[K_EXP] = s; seg[K_EXP] = s; tp[K_EXP] = t2;
    }
    __syncthreads();
    if (k < K_EXP) {
        int s0 = sseg[k];
        for (int b = 0; b < NBLK; ++b) base[b * K_EXP + k] += s0;
    }
}

__global__ void k_order(const int* __restrict__ ids, const int* __restrict__ base,
                        int* __restrict__ order) {
    __shared__ int sid[256];
    int t = threadIdx.x;
    int i = blockIdx.x * 256 + t;
    int my = ids[i];
    sid[t] = my;
    __syncthreads();
    int rank = 0;
    for (int j = 0; j < t; ++j) rank += (sid[j] == my) ? 1 : 0;
    order[base[blockIdx.x * K_EXP + my] + rank] = i;
}

// ---------------- gather sorted rows into packed bf16 xs ----------------
__global__ void k_gather(const float* __restrict__ x, const int* __restrict__ order,
                         __hip_bfloat16* __restrict__ xs) {
    int idx = blockIdx.x * 256 + threadIdx.x;
    int p = idx >> 7;            // 128 groups of 4 per row
    int c4 = (idx & 127) << 2;
    int src = order[p];
    const float* sp = x + (size_t)src * (L_DIM + 1) + c4;
    __hip_bfloat16 v[4];
    v[0] = __float2bfloat16(sp[0]);
    v[1] = __float2bfloat16(sp[1]);
    v[2] = __float2bfloat16(sp[2]);
    v[3] = __float2bfloat16(sp[3]);
    *(uint2*)(xs + (size_t)p * L_DIM + c4) = *(uint2*)v;
}

// ---------------- weight transpose + fp32->bf16:  W[K][N] -> Wt[N][K] ----------------
__global__ void k_transpose(const float* __restrict__ W, __hip_bfloat16* __restrict__ Wt,
                            int KDim, int NDim) {
    __shared__ float tile[32][33];
    int k0 = blockIdx.x << 5, n0 = blockIdx.y << 5;
    const float* Wb = W + (size_t)blockIdx.z * KDim * NDim;
    __hip_bfloat16* Wtb = Wt + (size_t)blockIdx.z * KDim * NDim;
    int tx = threadIdx.x & 31, ty = threadIdx.x >> 5;
    for (int i = ty; i < 32; i += 8)
        tile[i][tx] = Wb[(size_t)(k0 + i) * NDim + n0 + tx];
    __syncthreads();
    for (int i = ty; i < 32; i += 8)
        Wtb[(size_t)(n0 + i) * KDim + k0 + tx] = __float2bfloat16(tile[tx][i]);
}

// ---------------- bf16 MFMA GEMM ----------------
// C[M,N] = epi(A[M,K] @ Bt[N,K]^T + bias), 128x128 tile, BK=32, 4 waves (2x2),
// per-wave 4x4 fragments of 16x16x32. LDS double-buffered, global_load_lds w=16,
// kslot XOR swizzle (pre-swizzled global source, swizzled ds_read).
template <int KD, int ND, bool GROUPED, bool LEAKY, bool OUT_BF16>
__launch_bounds__(256)
__global__ void gemm_mfma(const __hip_bfloat16* __restrict__ A,
                          const __hip_bfloat16* __restrict__ Bt,
                          const float* __restrict__ bias,
                          void* __restrict__ Cout,
                          const int* __restrict__ seg, const int* __restrict__ tp) {
    __shared__ __align__(16) __hip_bfloat16 smem[2 * 2 * 128 * 32];  // 32 KB
    const int t = threadIdx.x;
    const int w = t >> 6, l = t & 63;
    const int n0 = blockIdx.y << 7;
    int m0, mEnd;
    const __hip_bfloat16* Bp = Bt;
    const float* bp = bias;
    if (GROUPED) {
        int bx = blockIdx.x;
        if (bx >= tp[K_EXP]) return;
        int e = 0;
        while (bx >= tp[e + 1]) ++e;
        m0 = seg[e] + ((bx - tp[e]) << 7);
        mEnd = seg[e + 1];
        Bp += (size_t)e * KD * ND;
        bp += (size_t)e * ND;
    } else {
        m0 = blockIdx.x << 7;
        mEnd = m0 + 128;
    }
    const int wm = w >> 1, wn = w & 1;
    const int g = l >> 4, li = l & 15;

    f32x4 acc[4][4];
#pragma unroll
    for (int i = 0; i < 4; ++i)
#pragma unroll
        for (int j = 0; j < 4; ++j) acc[i][j] = (f32x4){0.f, 0.f, 0.f, 0.f};

    // staging: wave w loads chunks 2w,2w+1 of A tile and of B tile.
    // chunk q: lane l -> row r=q*16+(l>>2), lds kslot s=l&3, global kslot s^((r>>1)&3)
    auto stage = [&](int buf, int kt) {
#pragma unroll
        for (int qi = 0; qi < 2; ++qi) {
            int q = 2 * w + qi;
            int r = q * 16 + (l >> 2);
            int s = l & 3;
            int ksg = s ^ ((r >> 1) & 3);
            int rowg = m0 + r;
            if (GROUPED) rowg = min(rowg, B_ROWS - 1);
            const __hip_bfloat16* src = A + (size_t)rowg * KD + kt * 32 + ksg * 8;
            gload16(src, &smem[(buf * 2 + 0) * 4096 + q * 512]);
        }
#pragma unroll
        for (int qi = 0; qi < 2; ++qi) {
            int q = 2 * w + qi;
            int rc = q * 16 + (l >> 2);
            int s = l & 3;
            int ksg = s ^ ((rc >> 1) & 3);
            const __hip_bfloat16* src = Bp + (size_t)(n0 + rc) * KD + kt * 32 + ksg * 8;
            gload16(src, &smem[(buf * 2 + 1) * 4096 + q * 512]);
        }
    };

    constexpr int NK = KD / 32;
    stage(0, 0);
    for (int kt = 0; kt < NK; ++kt) {
        int buf = kt & 1;
        __syncthreads();                       // tile kt resident (vmcnt drain + barrier)
        if (kt + 1 < NK) stage(buf ^ 1, kt + 1);  // prefetch next tile during compute
        bf16x8 af[4], bfr[4];
#pragma unroll
        for (int fm = 0; fm < 4; ++fm) {
            int rr = wm * 64 + fm * 16 + li;
            int ss = g ^ ((rr >> 1) & 3);
            af[fm] = *(const bf16x8*)&smem[(buf * 2 + 0) * 4096 + rr * 32 + ss * 8];
        }
#pragma unroll
        for (int fn = 0; fn < 4; ++fn) {
            int cc = wn * 64 + fn * 16 + li;
            int ss = g ^ ((cc >> 1) & 3);
            bfr[fn] = *(const bf16x8*)&smem[(buf * 2 + 1) * 4096 + cc * 32 + ss * 8];
        }
#pragma unroll
        for (int fm = 0; fm < 4; ++fm)
#pragma unroll
            for (int fn = 0; fn < 4; ++fn)
                acc[fm][fn] = __builtin_amdgcn_mfma_f32_16x16x32_bf16(
                    af[fm], bfr[fn], acc[fm][fn], 0, 0, 0);
    }

    // epilogue: C/D layout col=lane&15, row=(lane>>4)*4+reg
    float bv[4];
#pragma unroll
    for (int fn = 0; fn < 4; ++fn) bv[fn] = bp[n0 + wn * 64 + fn * 16 + li];
#pragma unroll
    for (int fm = 0; fm < 4; ++fm) {
#pragma unroll
        for (int i = 0; i < 4; ++i) {
            int r = m0 + wm * 64 + fm * 16 + g * 4 + i;
            if (!GROUPED || r < mEnd) {
#pragma unroll
                for (int fn = 0; fn < 4; ++fn) {
                    float v = acc[fm][fn][i] + bv[fn];
                    if (LEAKY) v = v > 0.f ? v : 0.01f * v;
                    size_t off = (size_t)r * ND + n0 + wn * 64 + fn * 16 + li;
                    if (OUT_BF16)
                        ((__hip_bfloat16*)Cout)[off] = __float2bfloat16(v);
                    else
                        ((float*)Cout)[off] = v;
                }
            }
        }
    }
}

extern "C" void kernel_launch(void* const* d_in, const int* in_sizes, int n_in,
                              void* d_out, int out_size, void* d_ws, size_t ws_size,
                              hipStream_t stream) {
    (void)in_sizes; (void)n_in; (void)out_size; (void)ws_size;
    const float* x   = (const float*)d_in[0];
    const float* We1 = (const float*)d_in[1];
    const float* be1 = (const float*)d_in[2];
    const float* We2 = (const float*)d_in[3];
    const float* be2 = (const float*)d_in[4];
    const float* Wd1 = (const float*)d_in[5];
    const float* bd1 = (const float*)d_in[6];
    const float* Wd2 = (const float*)d_in[7];
    const float* bd2 = (const float*)d_in[8];
    float* out = (float*)d_out;

    char* w = (char*)d_ws;
    auto alloc = [&](size_t bytes) {
        char* p = w;
        w += (bytes + 255) & ~(size_t)255;
        return p;
    };
    int* ids   = (int*)alloc((size_t)B_ROWS * 4);
    int* order = (int*)alloc((size_t)B_ROWS * 4);
    int* hist  = (int*)alloc((size_t)NBLK * K_EXP * 4);
    int* base  = (int*)alloc((size_t)NBLK * K_EXP * 4);
    int* seg   = (int*)alloc((K_EXP + 1) * 4);
    int* tp    = (int*)alloc((K_EXP + 1) * 4);
    __hip_bfloat16* xs   = (__hip_bfloat16*)alloc((size_t)B_ROWS * L_DIM * 2);  // 32 MB
    __hip_bfloat16* hbuf = (__hip_bfloat16*)alloc((size_t)B_ROWS * H_DIM * 2);  // 64 MB (h, then hd)
    __hip_bfloat16* zbuf = (__hip_bfloat16*)alloc((size_t)B_ROWS * E_DIM * 2);  // 8 MB
    __hip_bfloat16* Wt1  = (__hip_bfloat16*)alloc((size_t)L_DIM * H_DIM * 2);
    __hip_bfloat16* Wt2  = (__hip_bfloat16*)alloc((size_t)H_DIM * E_DIM * 2);
    __hip_bfloat16* Wd1t = (__hip_bfloat16*)alloc((size_t)K_EXP * E_DIM * H_DIM * 2);
    __hip_bfloat16* Wd2t = (__hip_bfloat16*)alloc((size_t)K_EXP * H_DIM * L_DIM * 2);

    k_ids_hist<<<NBLK, 256, 0, stream>>>(x, ids, hist);
    k_scan<<<1, 64, 0, stream>>>(hist, base, seg, tp);
    k_order<<<NBLK, 256, 0, stream>>>(ids, base, order);
    k_gather<<<(B_ROWS * (L_DIM / 4)) / 256, 256, 0, stream>>>(x, order, xs);

    k_transpose<<<dim3(L_DIM / 32, H_DIM / 32, 1), 256, 0, stream>>>(We1, Wt1, L_DIM, H_DIM);
    k_transpose<<<dim3(H_DIM / 32, E_DIM / 32, 1), 256, 0, stream>>>(We2, Wt2, H_DIM, E_DIM);
    k_transpose<<<dim3(E_DIM / 32, H_DIM / 32, K_EXP), 256, 0, stream>>>(Wd1, Wd1t, E_DIM, H_DIM);
    k_transpose<<<dim3(H_DIM / 32, L_DIM / 32, K_EXP), 256, 0, stream>>>(Wd2, Wd2t, H_DIM, L_DIM);

    // h = leaky(xs @ We1 + be1)
    gemm_mfma<L_DIM, H_DIM, false, true, true>
        <<<dim3(B_ROWS / 128, H_DIM / 128), 256, 0, stream>>>(xs, Wt1, be1, hbuf, nullptr, nullptr);
    // z = leaky(h @ We2 + be2)
    gemm_mfma<H_DIM, E_DIM, false, true, true>
        <<<dim3(B_ROWS / 128, E_DIM / 128), 256, 0, stream>>>(hbuf, Wt2, be2, zbuf, nullptr, nullptr);
    // hd = leaky(z @ Wd1[e] + bd1[e])   grouped
    gemm_mfma<E_DIM, H_DIM, true, true, true>
        <<<dim3(B_ROWS / 128 + K_EXP, H_DIM / 128), 256, 0, stream>>>(zbuf, Wd1t, bd1, hbuf, seg, tp);
    // out = hd @ Wd2[e] + bd2[e]        grouped, fp32 out
    gemm_mfma<H_DIM, L_DIM, true, false, false>
        <<<dim3(B_ROWS / 128 + K_EXP, L_DIM / 128), 256, 0, stream>>>(hbuf, Wd2t, bd2, out, seg, tp);
}